// Round 9
// baseline (1840.134 us; speedup 1.0000x reference)
//
#include <hip/hip_runtime.h>
#include <math.h>

#define HH 7
#define WW 18
#define PP 126        // HH*WW
#define CC 16
#define NN 4096
#define EE 16384
#define BB 64
#define TILE 2016               // CC*PP, std layout
#define ZT 2880                 // 16*9*20 haloed tile (An/Ae layout)

__device__ __forceinline__ float sp_f(float x) {
    // softplus, JAX-stable form: max(x,0)+log1p(exp(-|x|))
    return fmaxf(x, 0.f) + log1pf(expf(-fabsf(x)));
}

// ---------------- weight packs -> [tap][ci][cb][4] --------------------------
// lin (32 co): q=0 filter(cb), q=1 core(cb) [row cb+16], q=2 filter(cb+8), q=3 core(cb+8) [row cb+24]
__global__ void k_wT_lin(const float* __restrict__ w, float* __restrict__ wT) {
    int i = blockIdx.x * 256 + threadIdx.x;
    if (i < 4608) {
        int q = i & 3, cb = (i >> 2) & 7, ci = (i >> 5) & 15, tap = i >> 9;
        int co = cb + ((q >> 1) & 1) * 8 + (q & 1) * 16;
        wT[i] = w[(co * 16 + ci) * 9 + tap];
    }
}
// node/edge dual: q=0 wN(cb), q=1 wE(cb), q=2 wN(cb+8), q=3 wE(cb+8)
__global__ void k_wT_ne(const float* __restrict__ wN, const float* __restrict__ wE,
                        float* __restrict__ wT) {
    int i = blockIdx.x * 256 + threadIdx.x;
    if (i < 4608) {
        int q = i & 3, cb = (i >> 2) & 7, ci = (i >> 5) & 15, tap = i >> 9;
        int co = cb + ((q >> 1) & 1) * 8;
        const float* src = (q & 1) ? wE : wN;
        wT[i] = src[(co * 16 + ci) * 9 + tap];
    }
}

// ---------------- embedding -------------------------------------------------
__global__ __launch_bounds__(256) void k_embed(const float* __restrict__ nodes,
                                               const float* __restrict__ w,
                                               const float* __restrict__ b,
                                               float* __restrict__ atom) {
    __shared__ float tile[PP];
    __shared__ float ws[CC * 9];
    __shared__ float bs[CC];
    int n = blockIdx.x, tid = threadIdx.x;
    for (int i = tid; i < PP; i += 256) tile[i] = nodes[n * PP + i];
    for (int i = tid; i < CC * 9; i += 256) ws[i] = w[i];
    if (tid < CC) bs[tid] = b[tid];
    __syncthreads();
    for (int i = tid; i < CC * PP; i += 256) {
        int c = i / PP, p = i - c * PP, y = p / WW, x = p - (p / WW) * WW;
        float acc = bs[c];
#pragma unroll
        for (int dy = 0; dy < 3; dy++) {
            int yy = y + dy - 1; if ((unsigned)yy >= (unsigned)HH) continue;
#pragma unroll
            for (int dx = 0; dx < 3; dx++) {
                int xx = x + dx - 1; if ((unsigned)xx >= (unsigned)WW) continue;
                acc += tile[yy * WW + xx] * ws[c * 9 + dy * 3 + dx];
            }
        }
        atom[(size_t)n * CC * PP + i] = sp_f(acc);
    }
}

// ---------------- 2-co branch-free fp32 conv core ---------------------------
// zt: haloed tile [16 ci][9 rows][20 cols], halos zero. ws: [9][16][8][4].
// Thread computes channels cb and cb+8; outputs f0/c0 (cb) and f1/c1 (cb+8).
__device__ __forceinline__ void conv_body4(const float* zt,
                                           const float (*ws)[16][8][4],
                                           int cb, int y,
                                           float* f0, float* c0,
                                           float* f1, float* c1) {
    for (int ci = 0; ci < 16; ci++) {
        const float* zb = zt + ci * 180 + y * 20;
#pragma unroll
        for (int dy = 0; dy < 3; dy++) {
            const float* zr = zb + dy * 20;
            float4 q0 = *(const float4*)&zr[0];
            float4 q1 = *(const float4*)&zr[4];
            float4 q2 = *(const float4*)&zr[8];
            float4 q3 = *(const float4*)&zr[12];
            float4 q4 = *(const float4*)&zr[16];
            float r[20];
            r[0]=q0.x; r[1]=q0.y; r[2]=q0.z; r[3]=q0.w;
            r[4]=q1.x; r[5]=q1.y; r[6]=q1.z; r[7]=q1.w;
            r[8]=q2.x; r[9]=q2.y; r[10]=q2.z; r[11]=q2.w;
            r[12]=q3.x; r[13]=q3.y; r[14]=q3.z; r[15]=q3.w;
            r[16]=q4.x; r[17]=q4.y; r[18]=q4.z; r[19]=q4.w;
            float4 w0 = *(const float4*)&ws[dy * 3 + 0][ci][cb][0];
            float4 w1 = *(const float4*)&ws[dy * 3 + 1][ci][cb][0];
            float4 w2 = *(const float4*)&ws[dy * 3 + 2][ci][cb][0];
#pragma unroll
            for (int x = 0; x < 18; x++) {
                f0[x] = fmaf(r[x],     w0.x, f0[x]);
                c0[x] = fmaf(r[x],     w0.y, c0[x]);
                f1[x] = fmaf(r[x],     w0.z, f1[x]);
                c1[x] = fmaf(r[x],     w0.w, c1[x]);
                f0[x] = fmaf(r[x + 1], w1.x, f0[x]);
                c0[x] = fmaf(r[x + 1], w1.y, c0[x]);
                f1[x] = fmaf(r[x + 1], w1.z, f1[x]);
                c1[x] = fmaf(r[x + 1], w1.w, c1[x]);
                f0[x] = fmaf(r[x + 2], w2.x, f0[x]);
                c0[x] = fmaf(r[x + 2], w2.y, c0[x]);
                f1[x] = fmaf(r[x + 2], w2.z, f1[x]);
                c1[x] = fmaf(r[x + 2], w2.w, c1[x]);
            }
        }
    }
}

// ------------- per-node dual conv, 4 nodes/block; An/Ae OUT halo layout -----
__global__ __launch_bounds__(256) void k_node_conv2(const float* __restrict__ atom,
                                                    const float* __restrict__ wT,
                                                    float* __restrict__ An,
                                                    float* __restrict__ Ae) {
    __shared__ __align__(16) float zf[4 * ZT];        // 46080 B
    __shared__ __align__(16) float ws4[9][16][8][4];  // 18432 B
    int tid = threadIdx.x;
    int n0 = blockIdx.x * 4;
    for (int i = tid; i < 4 * ZT; i += 256) {
        int e2 = i / ZT, r = i - e2 * ZT;
        int ci = r / 180, rr = r - ci * 180;
        int yy = rr / 20, xx = rr - yy * 20;
        float v = 0.f;
        if ((unsigned)(yy - 1) < 7u && (unsigned)(xx - 1) < 18u)
            v = atom[(size_t)(n0 + e2) * TILE + ci * 126 + (yy - 1) * 18 + (xx - 1)];
        zf[i] = v;
    }
    for (int i = tid; i < 4608; i += 256) ((float*)ws4)[i] = wT[i];
    __syncthreads();
    int we = tid >> 6, lane = tid & 63;
    int cb = lane & 7, y = lane >> 3;
    bool act = y < 7;
    float f0[18], c0[18], f1[18], c1[18];
#pragma unroll
    for (int x = 0; x < 18; x++) { f0[x] = 0.f; c0[x] = 0.f; f1[x] = 0.f; c1[x] = 0.f; }
    if (act) conv_body4(&zf[we * ZT], ws4, cb, y, f0, c0, f1, c1);
    __syncthreads();
    // zero zf (halo zeros), stage An (f0->cb, f1->cb+8), write; then Ae
    for (int i = tid; i < 4 * ZT; i += 256) zf[i] = 0.f;
    __syncthreads();
    int b0 = we * ZT + cb * 180 + (y + 1) * 20 + 1;
    int b1 = we * ZT + (cb + 8) * 180 + (y + 1) * 20 + 1;
    if (act) {
#pragma unroll
        for (int x = 0; x < 18; x++) { zf[b0 + x] = f0[x]; zf[b1 + x] = f1[x]; }
    }
    __syncthreads();
    for (int i = tid; i < 4 * (ZT / 4); i += 256) {
        int e2 = i / (ZT / 4), j = i - e2 * (ZT / 4);
        ((float4*)&An[(size_t)(n0 + e2) * ZT])[j] = ((const float4*)zf)[i];
    }
    __syncthreads();
    // interior fully rewritten by same threads; halos still zero
    if (act) {
#pragma unroll
        for (int x = 0; x < 18; x++) { zf[b0 + x] = c0[x]; zf[b1 + x] = c1[x]; }
    }
    __syncthreads();
    for (int i = tid; i < 4 * (ZT / 4); i += 256) {
        int e2 = i / (ZT / 4), j = i - e2 * (ZT / 4);
        ((float4*)&Ae[(size_t)(n0 + e2) * ZT])[j] = ((const float4*)zf)[i];
    }
}

// ---------------- per-edge conv, 4 edges/block; An/Ae IN halo layout --------
__global__ __launch_bounds__(256) void k_edge(const float* __restrict__ An,
                                              const float* __restrict__ Ae,
                                              const int* __restrict__ es,
                                              const int* __restrict__ et,
                                              const float* __restrict__ wT,
                                              const float* __restrict__ lb,
                                              float* __restrict__ outb) {
    __shared__ __align__(16) float zf[4 * ZT];        // 46080 B
    __shared__ __align__(16) float ws4[9][16][8][4];  // 18432 B
    int tid = threadIdx.x;
    int e0 = blockIdx.x * 4;
    int s0 = es[e0], s1 = es[e0 + 1], s2 = es[e0 + 2], s3 = es[e0 + 3];
    int t0 = et[e0], t1 = et[e0 + 1], t2 = et[e0 + 2], t3 = et[e0 + 3];
    // pure float4 load: halos 0*0 -> elu(0)=0 preserved
    for (int i = tid; i < 4 * (ZT / 4); i += 256) {
        int e2 = i / (ZT / 4), j = i - e2 * (ZT / 4);
        int s = (e2 & 2) ? ((e2 & 1) ? s3 : s2) : ((e2 & 1) ? s1 : s0);
        int t = (e2 & 2) ? ((e2 & 1) ? t3 : t2) : ((e2 & 1) ? t1 : t0);
        float4 a4 = ((const float4*)&An[(size_t)s * ZT])[j];
        float4 b4 = ((const float4*)&Ae[(size_t)t * ZT])[j];
        float4 res;
        res.x = a4.x * b4.x; res.x = res.x > 0.f ? res.x : expm1f(res.x);
        res.y = a4.y * b4.y; res.y = res.y > 0.f ? res.y : expm1f(res.y);
        res.z = a4.z * b4.z; res.z = res.z > 0.f ? res.z : expm1f(res.z);
        res.w = a4.w * b4.w; res.w = res.w > 0.f ? res.w : expm1f(res.w);
        ((float4*)zf)[i] = res;
    }
    for (int i = tid; i < 4608; i += 256) ((float*)ws4)[i] = wT[i];
    __syncthreads();
    int we = tid >> 6, lane = tid & 63;
    int cb = lane & 7, y = lane >> 3;
    bool act = y < 7;
    float f0[18], c0[18], f1[18], c1[18];
#pragma unroll
    for (int x = 0; x < 18; x++) { f0[x] = 0.f; c0[x] = 0.f; f1[x] = 0.f; c1[x] = 0.f; }
    if (act) conv_body4(&zf[we * ZT], ws4, cb, y, f0, c0, f1, c1);
    __syncthreads();
    // stage msg in std layout (zf dead), then coalesced atomic scatter
    float* msgL = zf;
    if (act) {
        float bf0 = lb[cb], bc0 = lb[cb + 16], bf1 = lb[cb + 8], bc1 = lb[cb + 24];
        int base0 = we * TILE + cb * 126 + y * 18;
        int base1 = we * TILE + (cb + 8) * 126 + y * 18;
#pragma unroll
        for (int x = 0; x < 18; x++) {
            float hf0 = f0[x] + bf0, hc0 = c0[x] + bc0;
            float hf1 = f1[x] + bf1, hc1 = c1[x] + bc1;
            msgL[base0 + x] = (1.f / (1.f + expf(-hf0))) * sp_f(hc0);
            msgL[base1 + x] = (1.f / (1.f + expf(-hf1))) * sp_f(hc1);
        }
    }
    __syncthreads();
    for (int i = tid; i < 4 * TILE; i += 256) {
        int e2 = i / TILE, j = i - e2 * TILE;
        int s = (e2 & 2) ? ((e2 & 1) ? s3 : s2) : ((e2 & 1) ? s1 : s0);
        unsafeAtomicAdd(&outb[(size_t)s * TILE + j], msgL[i]);
    }
}

// ---------------- BN statistics (double accumulation) -----------------------
template <int C, int S>
__global__ void k_bn_stats(const float* __restrict__ X, double* __restrict__ acc, int M) {
    int c = blockIdx.y, tid = threadIdx.x;
    double s1 = 0.0, s2 = 0.0;
    for (int m = blockIdx.x; m < M; m += gridDim.x) {
        const float* xr = &X[((size_t)m * C + c) * S];
        for (int s = tid; s < S; s += blockDim.x) {
            float v = xr[s];
            s1 += v; s2 += (double)v * v;
        }
    }
    __shared__ double sh1[256], sh2[256];
    sh1[tid] = s1; sh2[tid] = s2;
    __syncthreads();
    for (int off = blockDim.x >> 1; off > 0; off >>= 1) {
        if (tid < off) { sh1[tid] += sh1[tid + off]; sh2[tid] += sh2[tid + off]; }
        __syncthreads();
    }
    if (tid == 0) {
        unsafeAtomicAdd(&acc[2 * c], sh1[0]);
        unsafeAtomicAdd(&acc[2 * c + 1], sh2[0]);
    }
}

__global__ void k_bn_fin(const double* __restrict__ acc, const float* __restrict__ g,
                         const float* __restrict__ b, double invn,
                         float* __restrict__ scl, float* __restrict__ shf) {
    int c = threadIdx.x;
    if (c < 16) {
        double m = acc[2 * c] * invn;
        double v = acc[2 * c + 1] * invn - m * m;
        double s = (double)g[c] / sqrt(v + 1e-5);
        scl[c] = (float)s;
        shf[c] = (float)((double)b[c] - s * m);
    }
}

__global__ __launch_bounds__(256) void k_bn_res(float* __restrict__ atom,
                                                const float* __restrict__ outb,
                                                const float* __restrict__ scl,
                                                const float* __restrict__ shf) {
    __shared__ float sc[16], sh[16];
    int tid = threadIdx.x;
    if (tid < 16) { sc[tid] = scl[tid]; sh[tid] = shf[tid]; }
    __syncthreads();
    const long total = (long)NN * CC * PP;
    for (long i = (long)blockIdx.x * blockDim.x + tid; i < total;
         i += (long)gridDim.x * blockDim.x) {
        int c = (int)((i / PP) & 15);
        atom[i] += sc[c] * outb[i] + sh[c];
    }
}

// ---------------- mean pooling over graphs (atomic) -------------------------
__global__ __launch_bounds__(256) void k_pool(const float* __restrict__ atom,
                                              const int* __restrict__ gi,
                                              float* __restrict__ crys) {
    int n = blockIdx.x;
    int g = gi[n];
    const float* a = &atom[(size_t)n * CC * PP];
    float* cr = &crys[(size_t)g * CC * PP];
    for (int i = threadIdx.x; i < CC * PP; i += 256) unsafeAtomicAdd(&cr[i], a[i]);
}

// ---------------- conv_to_fc ------------------------------------------------
__global__ __launch_bounds__(256) void k_ctf(const float* __restrict__ crys,
                                             const int* __restrict__ counts,
                                             const float* __restrict__ w,
                                             const float* __restrict__ b,
                                             float* __restrict__ flat) {
    __shared__ float tile[CC * PP];
    __shared__ float ws[CC * CC * 9];
    __shared__ float bs[CC];
    int g = blockIdx.x, tid = threadIdx.x;
    float cnt = (float)counts[g];
    for (int i = tid; i < CC * PP; i += 256) tile[i] = crys[(size_t)g * CC * PP + i] / cnt;
    for (int i = tid; i < CC * CC * 9; i += 256) ws[i] = w[i];
    if (tid < CC) bs[tid] = b[tid];
    __syncthreads();
    for (int i = tid; i < CC * PP; i += 256) {
        int co = i / PP, p = i - co * PP, y = p / WW, x = p - (p / WW) * WW;
        float acc = bs[co];
#pragma unroll
        for (int dy = 0; dy < 3; dy++) {
            int yy = y + dy - 1; if ((unsigned)yy >= (unsigned)HH) continue;
#pragma unroll
            for (int dx = 0; dx < 3; dx++) {
                int xx = x + dx - 1; if ((unsigned)xx >= (unsigned)WW) continue;
                int zoff = yy * WW + xx, tap = dy * 3 + dx;
                const float* tp = &tile[zoff];
                const float* wp = &ws[co * 144 + tap];
#pragma unroll
                for (int ci = 0; ci < CC; ci++) acc += tp[ci * PP] * wp[ci * 9];
            }
        }
        flat[(size_t)g * CC * PP + i] = sp_f(acc);
    }
}

// ---------------- space branch ----------------------------------------------
__global__ __launch_bounds__(256) void k_space1(const int* __restrict__ nsites,
                                                const int* __restrict__ sgs,
                                                const float* __restrict__ w1,
                                                const float* __restrict__ b1,
                                                const float* __restrict__ w2,
                                                const float* __restrict__ b2,
                                                const float* __restrict__ cw,
                                                const float* __restrict__ cb,
                                                float* __restrict__ sembp) {
    __shared__ float outer[256];
    __shared__ float row[16], col[16];
    __shared__ float cws[144], cbs[16];
    int g = blockIdx.x, tid = threadIdx.x;
    if (tid < 16) {
        float ns = (float)nsites[g], sg = (float)sgs[g];
        row[tid] = ns * w1[2 * tid] + sg * w1[2 * tid + 1] + b1[tid];
        col[tid] = ns * w2[2 * tid] + sg * w2[2 * tid + 1] + b2[tid];
        cbs[tid] = cb[tid];
    }
    if (tid >= 64 && tid < 64 + 144) cws[tid - 64] = cw[tid - 64];
    __syncthreads();
    outer[tid] = row[tid >> 4] * col[tid & 15];
    __syncthreads();
    for (int i = tid; i < 16 * 256; i += 256) {
        int c = i >> 8, p = i & 255, y = p >> 4, x = p & 15;
        float acc = cbs[c];
#pragma unroll
        for (int dy = 0; dy < 3; dy++) {
            int yy = y + dy - 1; if ((unsigned)yy >= 16u) continue;
#pragma unroll
            for (int dx = 0; dx < 3; dx++) {
                int xx = x + dx - 1; if ((unsigned)xx >= 16u) continue;
                acc += outer[yy * 16 + xx] * cws[c * 9 + dy * 3 + dx];
            }
        }
        sembp[(size_t)g * 4096 + i] = acc;
    }
}

__global__ __launch_bounds__(256) void k_bn_sp256(const float* __restrict__ X,
                                                  float* __restrict__ Y,
                                                  const float* __restrict__ scl,
                                                  const float* __restrict__ shf) {
    __shared__ float sc[16], sh[16];
    if (threadIdx.x < 16) { sc[threadIdx.x] = scl[threadIdx.x]; sh[threadIdx.x] = shf[threadIdx.x]; }
    __syncthreads();
    int total = BB * 16 * 256;
    for (int i = blockIdx.x * blockDim.x + threadIdx.x; i < total;
         i += gridDim.x * blockDim.x) {
        int c = (i >> 8) & 15;
        Y[i] = sp_f(sc[c] * X[i] + sh[c]);
    }
}

__global__ __launch_bounds__(256) void k_space_conv(const float* __restrict__ X,
                                                    const float* __restrict__ w,
                                                    const float* __restrict__ b,
                                                    float* __restrict__ Y) {
    __shared__ float tile[16 * 256];
    __shared__ float ws[2304], bs[16];
    int g = blockIdx.x, tid = threadIdx.x;
    for (int i = tid; i < 4096; i += 256) tile[i] = X[(size_t)g * 4096 + i];
    for (int i = tid; i < 2304; i += 256) ws[i] = w[i];
    if (tid < 16) bs[tid] = b[tid];
    __syncthreads();
    for (int i = tid; i < 4096; i += 256) {
        int c = i >> 8, p = i & 255, y = p >> 4, x = p & 15;
        float acc = bs[c];
#pragma unroll
        for (int dy = 0; dy < 3; dy++) {
            int yy = y + dy - 1; if ((unsigned)yy >= 16u) continue;
#pragma unroll
            for (int dx = 0; dx < 3; dx++) {
                int xx = x + dx - 1; if ((unsigned)xx >= 16u) continue;
                int tap = dy * 3 + dx;
                const float* wp = &ws[c * 144 + tap];
                const float* tp = &tile[yy * 16 + xx];
#pragma unroll
                for (int ci = 0; ci < 16; ci++) acc += tp[ci * 256] * wp[ci * 9];
            }
        }
        Y[(size_t)g * 4096 + i] = acc;
    }
}

__global__ __launch_bounds__(256) void k_space_tail(const float* __restrict__ ypre,
                                                    const float* __restrict__ scl,
                                                    const float* __restrict__ shf,
                                                    const float* __restrict__ fc3w,
                                                    const float* __restrict__ fc3b,
                                                    float* __restrict__ sout) {
    __shared__ float red[256];
    int g = blockIdx.x, tid = threadIdx.x;
    float val = 0.f;
    if (tid < 144) {
        int c = tid / 9, cell = tid - c * 9, py = cell / 3, px = cell - py * 3;
        float sc = scl[c], sh = shf[c];
        float mx = -INFINITY;
        const float* base = &ypre[((size_t)g * 16 + c) * 256];
        for (int yy = py * 5; yy < py * 5 + 5; yy++)
            for (int xx = px * 5; xx < px * 5 + 5; xx++)
                mx = fmaxf(mx, sc * base[yy * 16 + xx] + sh);
        val = sp_f(mx) * fc3w[tid];
    }
    red[tid] = val;
    __syncthreads();
    for (int off = 128; off > 0; off >>= 1) {
        if (tid < off) red[tid] += red[tid + off];
        __syncthreads();
    }
    if (tid == 0) sout[g] = red[0] + fc3b[0];
}

// ---------------- FC head ---------------------------------------------------
__global__ __launch_bounds__(256) void k_head(const float* __restrict__ flat,
                                              const float* __restrict__ fc1w,
                                              const float* __restrict__ fc1b,
                                              const float* __restrict__ fc2w,
                                              const float* __restrict__ fc2b,
                                              const float* __restrict__ regw,
                                              const float* __restrict__ regb,
                                              const float* __restrict__ sout,
                                              const float* __restrict__ eps,
                                              float* __restrict__ out) {
    int g = blockIdx.x, tid = threadIdx.x;
    __shared__ float h1[32], h2[32];
    int o = tid >> 3, r = tid & 7;
    float part = 0.f;
    const float* fr = &flat[(size_t)g * 2016];
    const float* wr = &fc1w[(size_t)o * 2016];
    for (int j = r; j < 2016; j += 8) part += fr[j] * wr[j];
    part += __shfl_down(part, 4, 8);
    part += __shfl_down(part, 2, 8);
    part += __shfl_down(part, 1, 8);
    if (r == 0) h1[o] = sp_f(part + fc1b[o]);
    __syncthreads();
    if (tid < 32) {
        float a = fc2b[tid];
        for (int j = 0; j < 32; j++) a += h1[j] * fc2w[tid * 32 + j];
        h2[tid] = sp_f(a);
    }
    __syncthreads();
    if (tid == 0) {
        float a = regb[0];
        for (int j = 0; j < 32; j++) a += h2[j] * regw[j];
        out[g] = a + eps[0] * sout[g];
    }
}

// ===========================================================================
extern "C" void kernel_launch(void* const* d_in, const int* in_sizes, int n_in,
                              void* d_out, int out_size, void* d_ws, size_t ws_size,
                              hipStream_t stream) {
    const float* nodes   = (const float*)d_in[0];
    const int*   es      = (const int*)d_in[1];
    const int*   et      = (const int*)d_in[2];
    const int*   gi      = (const int*)d_in[3];
    const int*   cnt     = (const int*)d_in[4];
    const int*   nsites  = (const int*)d_in[5];
    const int*   sgs     = (const int*)d_in[6];
    const float* emb_w   = (const float*)d_in[7];
    const float* emb_b   = (const float*)d_in[8];
    const float* cl_nw   = (const float*)d_in[9];
    const float* cl_ew   = (const float*)d_in[10];
    const float* cl_lw   = (const float*)d_in[11];
    const float* cl_lb   = (const float*)d_in[12];
    const float* cl_bg   = (const float*)d_in[13];
    const float* cl_bb   = (const float*)d_in[14];
    const float* se_w1   = (const float*)d_in[15];
    const float* se_b1   = (const float*)d_in[16];
    const float* se_w2   = (const float*)d_in[17];
    const float* se_b2   = (const float*)d_in[18];
    const float* se_cw   = (const float*)d_in[19];
    const float* se_cb   = (const float*)d_in[20];
    const float* se_bg   = (const float*)d_in[21];
    const float* se_bb   = (const float*)d_in[22];
    const float* sf_cw   = (const float*)d_in[23];
    const float* sf_cb   = (const float*)d_in[24];
    const float* sf_bg   = (const float*)d_in[25];
    const float* sf_bb   = (const float*)d_in[26];
    const float* ctf_w   = (const float*)d_in[27];
    const float* ctf_b   = (const float*)d_in[28];
    const float* fc1_w   = (const float*)d_in[29];
    const float* fc1_b   = (const float*)d_in[30];
    const float* fc2_w   = (const float*)d_in[31];
    const float* fc2_b   = (const float*)d_in[32];
    const float* reg_w   = (const float*)d_in[33];
    const float* reg_b   = (const float*)d_in[34];
    const float* fc3_w   = (const float*)d_in[35];
    const float* fc3_b   = (const float*)d_in[36];
    const float* eps     = (const float*)d_in[37];
    float* out = (float*)d_out;

    const size_t ATOM_B = (size_t)NN * TILE * sizeof(float);   // 33 MB
    const size_t HALO_B = (size_t)NN * ZT * sizeof(float);     // 47.2 MB
    char* ws = (char*)d_ws;
    float*  atom  = (float*)ws;              ws += ATOM_B;
    float*  An    = (float*)ws;              ws += HALO_B;
    float*  Ae    = (float*)ws;              ws += HALO_B;
    float*  outb  = (float*)ws;              ws += ATOM_B;
    double* acc   = (double*)ws;             ws += 256;
    float*  scl   = (float*)ws;              ws += 256;
    float*  shf   = (float*)ws;              ws += 256;
    float*  sout  = (float*)ws;              ws += 256;
    float*  nwT   = (float*)ws;              ws += 4608 * sizeof(float);
    float*  lwT   = (float*)ws;              ws += 4608 * sizeof(float);
    float*  crys  = (float*)ws;              ws += (size_t)BB * TILE * sizeof(float);
    float*  flat  = (float*)ws;              ws += (size_t)BB * TILE * sizeof(float);
    float*  sembp = (float*)ws;              ws += (size_t)BB * 16 * 256 * sizeof(float);
    float*  semb  = (float*)ws;              ws += (size_t)BB * 16 * 256 * sizeof(float);
    float*  ypre  = (float*)ws;              ws += (size_t)BB * 16 * 256 * sizeof(float);

    // ---- embedding
    k_embed<<<NN, 256, 0, stream>>>(nodes, emb_w, emb_b, atom);

    // ---- 3 conv layers (fp32 production path)
    for (int l = 0; l < 3; l++) {
        const float* nw = cl_nw + (size_t)l * CC * CC * 9;
        const float* ew = cl_ew + (size_t)l * CC * CC * 9;
        const float* lw = cl_lw + (size_t)l * 32 * CC * 9;
        const float* lb = cl_lb + (size_t)l * 32;
        const float* bg = cl_bg + (size_t)l * 16;
        const float* bb = cl_bb + (size_t)l * 16;

        k_wT_ne<<<18, 256, 0, stream>>>(nw, ew, nwT);
        k_wT_lin<<<18, 256, 0, stream>>>(lw, lwT);
        k_node_conv2<<<NN / 4, 256, 0, stream>>>(atom, nwT, An, Ae);
        hipMemcpyAsync(outb, atom, ATOM_B, hipMemcpyDeviceToDevice, stream);
        k_edge<<<EE / 4, 256, 0, stream>>>(An, Ae, es, et, lwT, lb, outb);
        hipMemsetAsync(acc, 0, 16 * 2 * sizeof(double), stream);
        k_bn_stats<16, 126><<<dim3(64, 16), 128, 0, stream>>>(outb, acc, NN);
        k_bn_fin<<<1, 16, 0, stream>>>(acc, bg, bb, 1.0 / ((double)NN * PP), scl, shf);
        k_bn_res<<<2048, 256, 0, stream>>>(atom, outb, scl, shf);
    }

    // ---- space branch
    k_space1<<<BB, 256, 0, stream>>>(nsites, sgs, se_w1, se_b1, se_w2, se_b2,
                                     se_cw, se_cb, sembp);
    hipMemsetAsync(acc, 0, 16 * 2 * sizeof(double), stream);
    k_bn_stats<16, 256><<<dim3(8, 16), 256, 0, stream>>>(sembp, acc, BB);
    k_bn_fin<<<1, 16, 0, stream>>>(acc, se_bg, se_bb, 1.0 / (BB * 256.0), scl, shf);
    k_bn_sp256<<<256, 256, 0, stream>>>(sembp, semb, scl, shf);
    k_space_conv<<<BB, 256, 0, stream>>>(semb, sf_cw, sf_cb, ypre);
    hipMemsetAsync(acc, 0, 16 * 2 * sizeof(double), stream);
    k_bn_stats<16, 256><<<dim3(8, 16), 256, 0, stream>>>(ypre, acc, BB);
    k_bn_fin<<<1, 16, 0, stream>>>(acc, sf_bg, sf_bb, 1.0 / (BB * 256.0), scl, shf);
    k_space_tail<<<BB, 256, 0, stream>>>(ypre, scl, shf, fc3_w, fc3_b, sout);

    // ---- pooling + conv_to_fc + head
    hipMemsetAsync(crys, 0, (size_t)BB * TILE * sizeof(float), stream);
    k_pool<<<NN, 256, 0, stream>>>(atom, gi, crys);
    k_ctf<<<BB, 256, 0, stream>>>(crys, cnt, ctf_w, ctf_b, flat);
    k_head<<<BB, 256, 0, stream>>>(flat, fc1_w, fc1_b, fc2_w, fc2_b,
                                   reg_w, reg_b, sout, eps, out);
}

// Round 10
// 1464.739 us; speedup vs baseline: 1.2563x; 1.2563x over previous
//
#include <hip/hip_runtime.h>
#include <math.h>

#define HH 7
#define WW 18
#define PP 126        // HH*WW
#define CC 16
#define NN 4096
#define EE 16384
#define BB 64
#define TILE 2016               // CC*PP, std layout
#define ZT 2880                 // 16*9*20 haloed tile (An/Ae layout)

// ---- fast transcendentals (hardware v_exp/v_log; abs err ~1e-7, thr 1.4e-3)
__device__ __forceinline__ float sp_f(float x) {
    // softplus: max(x,0) + log(1 + exp(-|x|))
    return fmaxf(x, 0.f) + __logf(1.f + __expf(-fabsf(x)));
}
__device__ __forceinline__ float elu_f(float v) {
    return v > 0.f ? v : __expf(v) - 1.f;
}
__device__ __forceinline__ float sigm_f(float x) {
    return 1.f / (1.f + __expf(-x));
}

// ---------------- weight packs -> [tap][ci][cb][4] --------------------------
// lin (32 co): q=0 filter(cb), q=1 core(cb) [row cb+16], q=2 filter(cb+8), q=3 core(cb+8)
__global__ void k_wT_lin(const float* __restrict__ w, float* __restrict__ wT) {
    int i = blockIdx.x * 256 + threadIdx.x;
    if (i < 4608) {
        int q = i & 3, cb = (i >> 2) & 7, ci = (i >> 5) & 15, tap = i >> 9;
        int co = cb + ((q >> 1) & 1) * 8 + (q & 1) * 16;
        wT[i] = w[(co * 16 + ci) * 9 + tap];
    }
}
// node/edge dual: q=0 wN(cb), q=1 wE(cb), q=2 wN(cb+8), q=3 wE(cb+8)
__global__ void k_wT_ne(const float* __restrict__ wN, const float* __restrict__ wE,
                        float* __restrict__ wT) {
    int i = blockIdx.x * 256 + threadIdx.x;
    if (i < 4608) {
        int q = i & 3, cb = (i >> 2) & 7, ci = (i >> 5) & 15, tap = i >> 9;
        int co = cb + ((q >> 1) & 1) * 8;
        const float* src = (q & 1) ? wE : wN;
        wT[i] = src[(co * 16 + ci) * 9 + tap];
    }
}

// ---------------- embedding -------------------------------------------------
__global__ __launch_bounds__(256) void k_embed(const float* __restrict__ nodes,
                                               const float* __restrict__ w,
                                               const float* __restrict__ b,
                                               float* __restrict__ atom) {
    __shared__ float tile[PP];
    __shared__ float ws[CC * 9];
    __shared__ float bs[CC];
    int n = blockIdx.x, tid = threadIdx.x;
    for (int i = tid; i < PP; i += 256) tile[i] = nodes[n * PP + i];
    for (int i = tid; i < CC * 9; i += 256) ws[i] = w[i];
    if (tid < CC) bs[tid] = b[tid];
    __syncthreads();
    for (int i = tid; i < CC * PP; i += 256) {
        int c = i / PP, p = i - c * PP, y = p / WW, x = p - (p / WW) * WW;
        float acc = bs[c];
#pragma unroll
        for (int dy = 0; dy < 3; dy++) {
            int yy = y + dy - 1; if ((unsigned)yy >= (unsigned)HH) continue;
#pragma unroll
            for (int dx = 0; dx < 3; dx++) {
                int xx = x + dx - 1; if ((unsigned)xx >= (unsigned)WW) continue;
                acc += tile[yy * WW + xx] * ws[c * 9 + dy * 3 + dx];
            }
        }
        atom[(size_t)n * CC * PP + i] = sp_f(acc);
    }
}

// ---------------- 2-co branch-free fp32 conv core ---------------------------
// zt: haloed tile [16 ci][9 rows][20 cols], halos zero. ws: [9][16][8][4].
__device__ __forceinline__ void conv_body4(const float* zt,
                                           const float (*ws)[16][8][4],
                                           int cb, int y,
                                           float* f0, float* c0,
                                           float* f1, float* c1) {
    for (int ci = 0; ci < 16; ci++) {
        const float* zb = zt + ci * 180 + y * 20;
#pragma unroll
        for (int dy = 0; dy < 3; dy++) {
            const float* zr = zb + dy * 20;
            float4 q0 = *(const float4*)&zr[0];
            float4 q1 = *(const float4*)&zr[4];
            float4 q2 = *(const float4*)&zr[8];
            float4 q3 = *(const float4*)&zr[12];
            float4 q4 = *(const float4*)&zr[16];
            float r[20];
            r[0]=q0.x; r[1]=q0.y; r[2]=q0.z; r[3]=q0.w;
            r[4]=q1.x; r[5]=q1.y; r[6]=q1.z; r[7]=q1.w;
            r[8]=q2.x; r[9]=q2.y; r[10]=q2.z; r[11]=q2.w;
            r[12]=q3.x; r[13]=q3.y; r[14]=q3.z; r[15]=q3.w;
            r[16]=q4.x; r[17]=q4.y; r[18]=q4.z; r[19]=q4.w;
            float4 w0 = *(const float4*)&ws[dy * 3 + 0][ci][cb][0];
            float4 w1 = *(const float4*)&ws[dy * 3 + 1][ci][cb][0];
            float4 w2 = *(const float4*)&ws[dy * 3 + 2][ci][cb][0];
#pragma unroll
            for (int x = 0; x < 18; x++) {
                f0[x] = fmaf(r[x],     w0.x, f0[x]);
                c0[x] = fmaf(r[x],     w0.y, c0[x]);
                f1[x] = fmaf(r[x],     w0.z, f1[x]);
                c1[x] = fmaf(r[x],     w0.w, c1[x]);
                f0[x] = fmaf(r[x + 1], w1.x, f0[x]);
                c0[x] = fmaf(r[x + 1], w1.y, c0[x]);
                f1[x] = fmaf(r[x + 1], w1.z, f1[x]);
                c1[x] = fmaf(r[x + 1], w1.w, c1[x]);
                f0[x] = fmaf(r[x + 2], w2.x, f0[x]);
                c0[x] = fmaf(r[x + 2], w2.y, c0[x]);
                f1[x] = fmaf(r[x + 2], w2.z, f1[x]);
                c1[x] = fmaf(r[x + 2], w2.w, c1[x]);
            }
        }
    }
}

// ------------- per-node dual conv: 1 node per WAVE, barrier-free ------------
// Single barrier (weights); each wave owns its LDS region end-to-end.
__global__ __launch_bounds__(256) void k_node_conv2(const float* __restrict__ atom,
                                                    const float* __restrict__ wT,
                                                    float* __restrict__ An,
                                                    float* __restrict__ Ae) {
    __shared__ __align__(16) float zf[4 * ZT];        // 46080 B
    __shared__ __align__(16) float ws4[9][16][8][4];  // 18432 B
    int tid = threadIdx.x;
    for (int i = tid; i < 4608; i += 256) ((float*)ws4)[i] = wT[i];
    __syncthreads();   // the only block barrier

    int we = tid >> 6, lane = tid & 63;
    int n = blockIdx.x * 4 + we;
    float* zw = &zf[we * ZT];
    const float* src = atom + (size_t)n * TILE;
    // wave-private halo-gather load (std -> halo layout, halos zero)
    for (int r = lane; r < ZT; r += 64) {
        int ci = r / 180, rr = r - ci * 180;
        int yy = rr / 20, xx = rr - yy * 20;
        float v = 0.f;
        if ((unsigned)(yy - 1) < 7u && (unsigned)(xx - 1) < 18u)
            v = src[ci * 126 + (yy - 1) * 18 + (xx - 1)];
        zw[r] = v;
    }
    int cb = lane & 7, y = lane >> 3;
    bool act = y < 7;
    float f0[18], c0[18], f1[18], c1[18];
#pragma unroll
    for (int x = 0; x < 18; x++) { f0[x] = 0.f; c0[x] = 0.f; f1[x] = 0.f; c1[x] = 0.f; }
    if (act) conv_body4(zw, ws4, cb, y, f0, c0, f1, c1);
    // re-stage outputs in own region (wave lockstep: conv reads done)
    for (int r = lane; r < ZT; r += 64) zw[r] = 0.f;
    int b0 = cb * 180 + (y + 1) * 20 + 1;
    int b1 = (cb + 8) * 180 + (y + 1) * 20 + 1;
    if (act) {
#pragma unroll
        for (int x = 0; x < 18; x++) { zw[b0 + x] = f0[x]; zw[b1 + x] = f1[x]; }
    }
    float4* an4 = (float4*)&An[(size_t)n * ZT];
    for (int j = lane; j < ZT / 4; j += 64) an4[j] = ((const float4*)zw)[j];
    if (act) {
#pragma unroll
        for (int x = 0; x < 18; x++) { zw[b0 + x] = c0[x]; zw[b1 + x] = c1[x]; }
    }
    float4* ae4 = (float4*)&Ae[(size_t)n * ZT];
    for (int j = lane; j < ZT / 4; j += 64) ae4[j] = ((const float4*)zw)[j];
}

// ---------------- per-edge conv: 1 edge per WAVE, barrier-free --------------
__global__ __launch_bounds__(256) void k_edge(const float* __restrict__ An,
                                              const float* __restrict__ Ae,
                                              const int* __restrict__ es,
                                              const int* __restrict__ et,
                                              const float* __restrict__ wT,
                                              const float* __restrict__ lb,
                                              float* __restrict__ outb) {
    __shared__ __align__(16) float zf[4 * ZT];        // 46080 B
    __shared__ __align__(16) float ws4[9][16][8][4];  // 18432 B
    int tid = threadIdx.x;
    for (int i = tid; i < 4608; i += 256) ((float*)ws4)[i] = wT[i];
    __syncthreads();   // the only block barrier

    int we = tid >> 6, lane = tid & 63;
    int e = blockIdx.x * 4 + we;
    int s = es[e], t = et[e];
    float* zw = &zf[we * ZT];
    const float4* an4 = (const float4*)&An[(size_t)s * ZT];
    const float4* ae4 = (const float4*)&Ae[(size_t)t * ZT];
    // wave-private float4 load+elu (halos 0*0 -> elu(0)=0)
    for (int j = lane; j < ZT / 4; j += 64) {
        float4 a4 = an4[j], b4 = ae4[j];
        float4 r;
        r.x = elu_f(a4.x * b4.x);
        r.y = elu_f(a4.y * b4.y);
        r.z = elu_f(a4.z * b4.z);
        r.w = elu_f(a4.w * b4.w);
        ((float4*)zw)[j] = r;
    }
    int cb = lane & 7, y = lane >> 3;
    bool act = y < 7;
    float f0[18], c0[18], f1[18], c1[18];
#pragma unroll
    for (int x = 0; x < 18; x++) { f0[x] = 0.f; c0[x] = 0.f; f1[x] = 0.f; c1[x] = 0.f; }
    if (act) conv_body4(zw, ws4, cb, y, f0, c0, f1, c1);
    // stage msg in own region, std layout [16ch][126] (wave lockstep: conv done)
    if (act) {
        float bf0 = lb[cb], bc0 = lb[cb + 16], bf1 = lb[cb + 8], bc1 = lb[cb + 24];
        int base0 = cb * 126 + y * 18;
        int base1 = (cb + 8) * 126 + y * 18;
#pragma unroll
        for (int x = 0; x < 18; x++) {
            zw[base0 + x] = sigm_f(f0[x] + bf0) * sp_f(c0[x] + bc0);
            zw[base1 + x] = sigm_f(f1[x] + bf1) * sp_f(c1[x] + bc1);
        }
    }
    // coalesced atomic scatter (wave-private)
    float* outn = outb + (size_t)s * TILE;
    for (int j = lane; j < TILE; j += 64)
        unsafeAtomicAdd(&outn[j], zw[j]);
}

// ---------------- BN statistics (double accumulation) -----------------------
template <int C, int S>
__global__ void k_bn_stats(const float* __restrict__ X, double* __restrict__ acc, int M) {
    int c = blockIdx.y, tid = threadIdx.x;
    double s1 = 0.0, s2 = 0.0;
    for (int m = blockIdx.x; m < M; m += gridDim.x) {
        const float* xr = &X[((size_t)m * C + c) * S];
        for (int s = tid; s < S; s += blockDim.x) {
            float v = xr[s];
            s1 += v; s2 += (double)v * v;
        }
    }
    __shared__ double sh1[256], sh2[256];
    sh1[tid] = s1; sh2[tid] = s2;
    __syncthreads();
    for (int off = blockDim.x >> 1; off > 0; off >>= 1) {
        if (tid < off) { sh1[tid] += sh1[tid + off]; sh2[tid] += sh2[tid + off]; }
        __syncthreads();
    }
    if (tid == 0) {
        unsafeAtomicAdd(&acc[2 * c], sh1[0]);
        unsafeAtomicAdd(&acc[2 * c + 1], sh2[0]);
    }
}

__global__ void k_bn_fin(const double* __restrict__ acc, const float* __restrict__ g,
                         const float* __restrict__ b, double invn,
                         float* __restrict__ scl, float* __restrict__ shf) {
    int c = threadIdx.x;
    if (c < 16) {
        double m = acc[2 * c] * invn;
        double v = acc[2 * c + 1] * invn - m * m;
        double s = (double)g[c] / sqrt(v + 1e-5);
        scl[c] = (float)s;
        shf[c] = (float)((double)b[c] - s * m);
    }
}

__global__ __launch_bounds__(256) void k_bn_res(float* __restrict__ atom,
                                                const float* __restrict__ outb,
                                                const float* __restrict__ scl,
                                                const float* __restrict__ shf) {
    __shared__ float sc[16], sh[16];
    int tid = threadIdx.x;
    if (tid < 16) { sc[tid] = scl[tid]; sh[tid] = shf[tid]; }
    __syncthreads();
    const long total = (long)NN * CC * PP;
    for (long i = (long)blockIdx.x * blockDim.x + tid; i < total;
         i += (long)gridDim.x * blockDim.x) {
        int c = (int)((i / PP) & 15);
        atom[i] += sc[c] * outb[i] + sh[c];
    }
}

// ---------------- mean pooling over graphs (atomic) -------------------------
__global__ __launch_bounds__(256) void k_pool(const float* __restrict__ atom,
                                              const int* __restrict__ gi,
                                              float* __restrict__ crys) {
    int n = blockIdx.x;
    int g = gi[n];
    const float* a = &atom[(size_t)n * CC * PP];
    float* cr = &crys[(size_t)g * CC * PP];
    for (int i = threadIdx.x; i < CC * PP; i += 256) unsafeAtomicAdd(&cr[i], a[i]);
}

// ---------------- conv_to_fc ------------------------------------------------
__global__ __launch_bounds__(256) void k_ctf(const float* __restrict__ crys,
                                             const int* __restrict__ counts,
                                             const float* __restrict__ w,
                                             const float* __restrict__ b,
                                             float* __restrict__ flat) {
    __shared__ float tile[CC * PP];
    __shared__ float ws[CC * CC * 9];
    __shared__ float bs[CC];
    int g = blockIdx.x, tid = threadIdx.x;
    float cnt = (float)counts[g];
    for (int i = tid; i < CC * PP; i += 256) tile[i] = crys[(size_t)g * CC * PP + i] / cnt;
    for (int i = tid; i < CC * CC * 9; i += 256) ws[i] = w[i];
    if (tid < CC) bs[tid] = b[tid];
    __syncthreads();
    for (int i = tid; i < CC * PP; i += 256) {
        int co = i / PP, p = i - co * PP, y = p / WW, x = p - (p / WW) * WW;
        float acc = bs[co];
#pragma unroll
        for (int dy = 0; dy < 3; dy++) {
            int yy = y + dy - 1; if ((unsigned)yy >= (unsigned)HH) continue;
#pragma unroll
            for (int dx = 0; dx < 3; dx++) {
                int xx = x + dx - 1; if ((unsigned)xx >= (unsigned)WW) continue;
                int zoff = yy * WW + xx, tap = dy * 3 + dx;
                const float* tp = &tile[zoff];
                const float* wp = &ws[co * 144 + tap];
#pragma unroll
                for (int ci = 0; ci < CC; ci++) acc += tp[ci * PP] * wp[ci * 9];
            }
        }
        flat[(size_t)g * CC * PP + i] = sp_f(acc);
    }
}

// ---------------- space branch ----------------------------------------------
__global__ __launch_bounds__(256) void k_space1(const int* __restrict__ nsites,
                                                const int* __restrict__ sgs,
                                                const float* __restrict__ w1,
                                                const float* __restrict__ b1,
                                                const float* __restrict__ w2,
                                                const float* __restrict__ b2,
                                                const float* __restrict__ cw,
                                                const float* __restrict__ cb,
                                                float* __restrict__ sembp) {
    __shared__ float outer[256];
    __shared__ float row[16], col[16];
    __shared__ float cws[144], cbs[16];
    int g = blockIdx.x, tid = threadIdx.x;
    if (tid < 16) {
        float ns = (float)nsites[g], sg = (float)sgs[g];
        row[tid] = ns * w1[2 * tid] + sg * w1[2 * tid + 1] + b1[tid];
        col[tid] = ns * w2[2 * tid] + sg * w2[2 * tid + 1] + b2[tid];
        cbs[tid] = cb[tid];
    }
    if (tid >= 64 && tid < 64 + 144) cws[tid - 64] = cw[tid - 64];
    __syncthreads();
    outer[tid] = row[tid >> 4] * col[tid & 15];
    __syncthreads();
    for (int i = tid; i < 16 * 256; i += 256) {
        int c = i >> 8, p = i & 255, y = p >> 4, x = p & 15;
        float acc = cbs[c];
#pragma unroll
        for (int dy = 0; dy < 3; dy++) {
            int yy = y + dy - 1; if ((unsigned)yy >= 16u) continue;
#pragma unroll
            for (int dx = 0; dx < 3; dx++) {
                int xx = x + dx - 1; if ((unsigned)xx >= 16u) continue;
                acc += outer[yy * 16 + xx] * cws[c * 9 + dy * 3 + dx];
            }
        }
        sembp[(size_t)g * 4096 + i] = acc;
    }
}

__global__ __launch_bounds__(256) void k_bn_sp256(const float* __restrict__ X,
                                                  float* __restrict__ Y,
                                                  const float* __restrict__ scl,
                                                  const float* __restrict__ shf) {
    __shared__ float sc[16], sh[16];
    if (threadIdx.x < 16) { sc[threadIdx.x] = scl[threadIdx.x]; sh[threadIdx.x] = shf[threadIdx.x]; }
    __syncthreads();
    int total = BB * 16 * 256;
    for (int i = blockIdx.x * blockDim.x + threadIdx.x; i < total;
         i += gridDim.x * blockDim.x) {
        int c = (i >> 8) & 15;
        Y[i] = sp_f(sc[c] * X[i] + sh[c]);
    }
}

__global__ __launch_bounds__(256) void k_space_conv(const float* __restrict__ X,
                                                    const float* __restrict__ w,
                                                    const float* __restrict__ b,
                                                    float* __restrict__ Y) {
    __shared__ float tile[16 * 256];
    __shared__ float ws[2304], bs[16];
    int g = blockIdx.x, tid = threadIdx.x;
    for (int i = tid; i < 4096; i += 256) tile[i] = X[(size_t)g * 4096 + i];
    for (int i = tid; i < 2304; i += 256) ws[i] = w[i];
    if (tid < 16) bs[tid] = b[tid];
    __syncthreads();
    for (int i = tid; i < 4096; i += 256) {
        int c = i >> 8, p = i & 255, y = p >> 4, x = p & 15;
        float acc = bs[c];
#pragma unroll
        for (int dy = 0; dy < 3; dy++) {
            int yy = y + dy - 1; if ((unsigned)yy >= 16u) continue;
#pragma unroll
            for (int dx = 0; dx < 3; dx++) {
                int xx = x + dx - 1; if ((unsigned)xx >= 16u) continue;
                int tap = dy * 3 + dx;
                const float* wp = &ws[c * 144 + tap];
                const float* tp = &tile[yy * 16 + xx];
#pragma unroll
                for (int ci = 0; ci < 16; ci++) acc += tp[ci * 256] * wp[ci * 9];
            }
        }
        Y[(size_t)g * 4096 + i] = acc;
    }
}

__global__ __launch_bounds__(256) void k_space_tail(const float* __restrict__ ypre,
                                                    const float* __restrict__ scl,
                                                    const float* __restrict__ shf,
                                                    const float* __restrict__ fc3w,
                                                    const float* __restrict__ fc3b,
                                                    float* __restrict__ sout) {
    __shared__ float red[256];
    int g = blockIdx.x, tid = threadIdx.x;
    float val = 0.f;
    if (tid < 144) {
        int c = tid / 9, cell = tid - c * 9, py = cell / 3, px = cell - py * 3;
        float sc = scl[c], sh = shf[c];
        float mx = -INFINITY;
        const float* base = &ypre[((size_t)g * 16 + c) * 256];
        for (int yy = py * 5; yy < py * 5 + 5; yy++)
            for (int xx = px * 5; xx < px * 5 + 5; xx++)
                mx = fmaxf(mx, sc * base[yy * 16 + xx] + sh);
        val = sp_f(mx) * fc3w[tid];
    }
    red[tid] = val;
    __syncthreads();
    for (int off = 128; off > 0; off >>= 1) {
        if (tid < off) red[tid] += red[tid + off];
        __syncthreads();
    }
    if (tid == 0) sout[g] = red[0] + fc3b[0];
}

// ---------------- FC head ---------------------------------------------------
__global__ __launch_bounds__(256) void k_head(const float* __restrict__ flat,
                                              const float* __restrict__ fc1w,
                                              const float* __restrict__ fc1b,
                                              const float* __restrict__ fc2w,
                                              const float* __restrict__ fc2b,
                                              const float* __restrict__ regw,
                                              const float* __restrict__ regb,
                                              const float* __restrict__ sout,
                                              const float* __restrict__ eps,
                                              float* __restrict__ out) {
    int g = blockIdx.x, tid = threadIdx.x;
    __shared__ float h1[32], h2[32];
    int o = tid >> 3, r = tid & 7;
    float part = 0.f;
    const float* fr = &flat[(size_t)g * 2016];
    const float* wr = &fc1w[(size_t)o * 2016];
    for (int j = r; j < 2016; j += 8) part += fr[j] * wr[j];
    part += __shfl_down(part, 4, 8);
    part += __shfl_down(part, 2, 8);
    part += __shfl_down(part, 1, 8);
    if (r == 0) h1[o] = sp_f(part + fc1b[o]);
    __syncthreads();
    if (tid < 32) {
        float a = fc2b[tid];
        for (int j = 0; j < 32; j++) a += h1[j] * fc2w[tid * 32 + j];
        h2[tid] = sp_f(a);
    }
    __syncthreads();
    if (tid == 0) {
        float a = regb[0];
        for (int j = 0; j < 32; j++) a += h2[j] * regw[j];
        out[g] = a + eps[0] * sout[g];
    }
}

// ===========================================================================
extern "C" void kernel_launch(void* const* d_in, const int* in_sizes, int n_in,
                              void* d_out, int out_size, void* d_ws, size_t ws_size,
                              hipStream_t stream) {
    const float* nodes   = (const float*)d_in[0];
    const int*   es      = (const int*)d_in[1];
    const int*   et      = (const int*)d_in[2];
    const int*   gi      = (const int*)d_in[3];
    const int*   cnt     = (const int*)d_in[4];
    const int*   nsites  = (const int*)d_in[5];
    const int*   sgs     = (const int*)d_in[6];
    const float* emb_w   = (const float*)d_in[7];
    const float* emb_b   = (const float*)d_in[8];
    const float* cl_nw   = (const float*)d_in[9];
    const float* cl_ew   = (const float*)d_in[10];
    const float* cl_lw   = (const float*)d_in[11];
    const float* cl_lb   = (const float*)d_in[12];
    const float* cl_bg   = (const float*)d_in[13];
    const float* cl_bb   = (const float*)d_in[14];
    const float* se_w1   = (const float*)d_in[15];
    const float* se_b1   = (const float*)d_in[16];
    const float* se_w2   = (const float*)d_in[17];
    const float* se_b2   = (const float*)d_in[18];
    const float* se_cw   = (const float*)d_in[19];
    const float* se_cb   = (const float*)d_in[20];
    const float* se_bg   = (const float*)d_in[21];
    const float* se_bb   = (const float*)d_in[22];
    const float* sf_cw   = (const float*)d_in[23];
    const float* sf_cb   = (const float*)d_in[24];
    const float* sf_bg   = (const float*)d_in[25];
    const float* sf_bb   = (const float*)d_in[26];
    const float* ctf_w   = (const float*)d_in[27];
    const float* ctf_b   = (const float*)d_in[28];
    const float* fc1_w   = (const float*)d_in[29];
    const float* fc1_b   = (const float*)d_in[30];
    const float* fc2_w   = (const float*)d_in[31];
    const float* fc2_b   = (const float*)d_in[32];
    const float* reg_w   = (const float*)d_in[33];
    const float* reg_b   = (const float*)d_in[34];
    const float* fc3_w   = (const float*)d_in[35];
    const float* fc3_b   = (const float*)d_in[36];
    const float* eps     = (const float*)d_in[37];
    float* out = (float*)d_out;

    const size_t ATOM_B = (size_t)NN * TILE * sizeof(float);   // 33 MB
    const size_t HALO_B = (size_t)NN * ZT * sizeof(float);     // 47.2 MB
    char* ws = (char*)d_ws;
    float*  atom  = (float*)ws;              ws += ATOM_B;
    float*  An    = (float*)ws;              ws += HALO_B;
    float*  Ae    = (float*)ws;              ws += HALO_B;
    float*  outb  = (float*)ws;              ws += ATOM_B;
    double* acc   = (double*)ws;             ws += 256;
    float*  scl   = (float*)ws;              ws += 256;
    float*  shf   = (float*)ws;              ws += 256;
    float*  sout  = (float*)ws;              ws += 256;
    float*  nwT   = (float*)ws;              ws += 4608 * sizeof(float);
    float*  lwT   = (float*)ws;              ws += 4608 * sizeof(float);
    float*  crys  = (float*)ws;              ws += (size_t)BB * TILE * sizeof(float);
    float*  flat  = (float*)ws;              ws += (size_t)BB * TILE * sizeof(float);
    float*  sembp = (float*)ws;              ws += (size_t)BB * 16 * 256 * sizeof(float);
    float*  semb  = (float*)ws;              ws += (size_t)BB * 16 * 256 * sizeof(float);
    float*  ypre  = (float*)ws;              ws += (size_t)BB * 16 * 256 * sizeof(float);

    // ---- embedding
    k_embed<<<NN, 256, 0, stream>>>(nodes, emb_w, emb_b, atom);

    // ---- 3 conv layers (fp32 production path)
    for (int l = 0; l < 3; l++) {
        const float* nw = cl_nw + (size_t)l * CC * CC * 9;
        const float* ew = cl_ew + (size_t)l * CC * CC * 9;
        const float* lw = cl_lw + (size_t)l * 32 * CC * 9;
        const float* lb = cl_lb + (size_t)l * 32;
        const float* bg = cl_bg + (size_t)l * 16;
        const float* bb = cl_bb + (size_t)l * 16;

        k_wT_ne<<<18, 256, 0, stream>>>(nw, ew, nwT);
        k_wT_lin<<<18, 256, 0, stream>>>(lw, lwT);
        k_node_conv2<<<NN / 4, 256, 0, stream>>>(atom, nwT, An, Ae);
        hipMemcpyAsync(outb, atom, ATOM_B, hipMemcpyDeviceToDevice, stream);
        k_edge<<<EE / 4, 256, 0, stream>>>(An, Ae, es, et, lwT, lb, outb);
        hipMemsetAsync(acc, 0, 16 * 2 * sizeof(double), stream);
        k_bn_stats<16, 126><<<dim3(64, 16), 128, 0, stream>>>(outb, acc, NN);
        k_bn_fin<<<1, 16, 0, stream>>>(acc, bg, bb, 1.0 / ((double)NN * PP), scl, shf);
        k_bn_res<<<2048, 256, 0, stream>>>(atom, outb, scl, shf);
    }

    // ---- space branch
    k_space1<<<BB, 256, 0, stream>>>(nsites, sgs, se_w1, se_b1, se_w2, se_b2,
                                     se_cw, se_cb, sembp);
    hipMemsetAsync(acc, 0, 16 * 2 * sizeof(double), stream);
    k_bn_stats<16, 256><<<dim3(8, 16), 256, 0, stream>>>(sembp, acc, BB);
    k_bn_fin<<<1, 16, 0, stream>>>(acc, se_bg, se_bb, 1.0 / (BB * 256.0), scl, shf);
    k_bn_sp256<<<256, 256, 0, stream>>>(sembp, semb, scl, shf);
    k_space_conv<<<BB, 256, 0, stream>>>(semb, sf_cw, sf_cb, ypre);
    hipMemsetAsync(acc, 0, 16 * 2 * sizeof(double), stream);
    k_bn_stats<16, 256><<<dim3(8, 16), 256, 0, stream>>>(ypre, acc, BB);
    k_bn_fin<<<1, 16, 0, stream>>>(acc, sf_bg, sf_bb, 1.0 / (BB * 256.0), scl, shf);
    k_space_tail<<<BB, 256, 0, stream>>>(ypre, scl, shf, fc3_w, fc3_b, sout);

    // ---- pooling + conv_to_fc + head
    hipMemsetAsync(crys, 0, (size_t)BB * TILE * sizeof(float), stream);
    k_pool<<<NN, 256, 0, stream>>>(atom, gi, crys);
    k_ctf<<<BB, 256, 0, stream>>>(crys, cnt, ctf_w, ctf_b, flat);
    k_head<<<BB, 256, 0, stream>>>(flat, fc1_w, fc1_b, fc2_w, fc2_b,
                                   reg_w, reg_b, sout, eps, out);
}